// Round 9
// baseline (1171.617 us; speedup 1.0000x reference)
//
#include <hip/hip_runtime.h>
#include <hip/hip_bf16.h>
#include <math.h>

#define NB 2048
#define NF 512
#define NM 16
#define NK 121
#define NMK 1936

typedef __attribute__((ext_vector_type(8))) short bf16x8;
typedef __attribute__((ext_vector_type(4))) float f32x4;

#define MFMA __builtin_amdgcn_mfma_f32_16x16x32_bf16

static __device__ __forceinline__ unsigned short f2b(float f) {
  unsigned int u = __float_as_uint(f);
  unsigned int lsb = (u >> 16) & 1u;
  u += 0x7fffu + lsb;
  return (unsigned short)(u >> 16);
}

// pack two f32 -> one dword of 2x bf16 (RNE), low = lo
static __device__ __forceinline__ unsigned cvtpk(float lo, float hi) {
  unsigned r;
  asm("v_cvt_pk_bf16_f32 %0, %1, %2" : "=v"(r) : "v"(lo), "v"(hi));
  return r;
}

// ---------------------------------------------------------------------------
// K0: pre-pack conv weights into per-wave MFMA A-fragment slices (bf16).
// ap1: [w(4)][kc(5)][m2(2)][lane(64)][j(8)]  -- wave w owns c1 in [32w,32w+32)
// ap2: [mt(4)][s(9)][kc(4)][lane(64)][j(8)]  -- wave mt owns c2 in [16mt,16mt+16)
// A[m][k]: m = lane&15, k = (lane>>4)*8 + j  (16x16x32 A-operand layout).
// NOTE: ap1 stores ZERO for s==9 (tail of padded K=160) -- k_fused relies on
// this to skip B-fragment masking for the invalid tap.
// ---------------------------------------------------------------------------
__global__ __launch_bounds__(256) void k_pack(
    const float* __restrict__ ck1, const float* __restrict__ ck2,
    unsigned short* __restrict__ ap1, unsigned short* __restrict__ ap2) {
  int i = blockIdx.x * 256 + threadIdx.x;
  if (i < 20480) {
    int j = i & 7, lane = (i >> 3) & 63;
    int m2 = (i >> 9) & 1, kc = (i >> 10) % 5, w = i / 5120;
    int c1 = w * 32 + m2 * 16 + (lane & 15);
    int k = kc * 32 + ((lane >> 4) << 3) + j;
    int s = k >> 4, ci = k & 15;
    float v = 0.f;
    if (s < 9) v = ck1[((c1 * 16 + ci) * 3 + s / 3) * 3 + (s % 3)];
    ap1[i] = f2b(v);
  }
  int i2 = i - 20480;
  if (i2 >= 0 && i2 < 73728) {
    int j = i2 & 7, lane = (i2 >> 3) & 63;
    int kc = (i2 >> 9) & 3, s = (i2 >> 11) % 9, mt = i2 / 18432;
    int c2 = mt * 16 + (lane & 15);
    int c1 = kc * 32 + ((lane >> 4) << 3) + j;
    float v = ck2[((c2 * 128 + c1) * 3 + s / 3) * 3 + (s % 3)];
    ap2[i2] = f2b(v);
  }
}

// ---------------------------------------------------------------------------
// K1: MLP  x=[features|pos_enc] (576) -> 256 -> 128 -> 1936 write_vals
// 4 rows/block (512 blocks = 2 blocks/CU, 8 waves/CU) + deep load-ILP.
// ---------------------------------------------------------------------------
__global__ __launch_bounds__(256) void k_mlp(
    const float* __restrict__ feat, const float* __restrict__ gaze,
    const float* __restrict__ w1, const float* __restrict__ b1,
    const float* __restrict__ w2, const float* __restrict__ b2,
    const float* __restrict__ wv, const float* __restrict__ bv,
    float* __restrict__ wvout) {
  __shared__ float xs[4][576];
  __shared__ float g1[4][256];
  __shared__ float g2[4][128];
  const int t = threadIdx.x;
  const int b0 = blockIdx.x * 4;

  for (int e = t; e < 4 * 512; e += 256) {
    int r = e >> 9, i = e & 511;
    xs[r][i] = feat[(size_t)(b0 + r) * NF + i];
  }
  if (t < 4 * 64) {
    int r = t >> 6, i = t & 63;
    int axis = i >> 5;
    int ii = i & 31;
    int jj = ii >> 1;
    int isc = ii & 1;
    float p = gaze[(size_t)(b0 + r) * 2 + axis];
    float dv = expf(-(float)(2 * jj) * 0.28782313662425575f);
    float ang = p * dv;
    xs[r][512 + i] = isc ? cosf(ang) : sinf(ang);
  }
  __syncthreads();
  {
    float acc[4];
    float bb = b1[t];
#pragma unroll
    for (int r = 0; r < 4; r++) acc[r] = bb;
#pragma unroll 8
    for (int i = 0; i < 576; i++) {
      float w = w1[(size_t)i * 256 + t];
#pragma unroll
      for (int r = 0; r < 4; r++) acc[r] = fmaf(xs[r][i], w, acc[r]);
    }
#pragma unroll
    for (int r = 0; r < 4; r++) g1[r][t] = fmaxf(acc[r], 0.f);
  }
  __syncthreads();
  if (t < 128) {
    float acc[4];
    float bb = b2[t];
#pragma unroll
    for (int r = 0; r < 4; r++) acc[r] = bb;
#pragma unroll 8
    for (int i = 0; i < 256; i++) {
      float w = w2[(size_t)i * 128 + t];
#pragma unroll
      for (int r = 0; r < 4; r++) acc[r] = fmaf(g1[r][i], w, acc[r]);
    }
#pragma unroll
    for (int r = 0; r < 4; r++) g2[r][t] = fmaxf(acc[r], 0.f);
  }
  __syncthreads();
  {
    float acc7[7][4];  // j = t + 256*jj, jj<7 (j <= 1791, always valid)
    float accT[4];     // j = 1792 + t, valid for t < 144
#pragma unroll
    for (int jj = 0; jj < 7; jj++) {
      float bb = bv[t + 256 * jj];
#pragma unroll
      for (int r = 0; r < 4; r++) acc7[jj][r] = bb;
    }
    {
      float bb = (t < 144) ? bv[1792 + t] : 0.f;
#pragma unroll
      for (int r = 0; r < 4; r++) accT[r] = bb;
    }
#pragma unroll 2
    for (int i = 0; i < 128; i++) {
      float g[4];
#pragma unroll
      for (int r = 0; r < 4; r++) g[r] = g2[r][i];
      const float* wrow = wv + (size_t)i * NMK;
#pragma unroll
      for (int jj = 0; jj < 7; jj++) {
        float w = wrow[t + 256 * jj];
#pragma unroll
        for (int r = 0; r < 4; r++) acc7[jj][r] = fmaf(g[r], w, acc7[jj][r]);
      }
      if (t < 144) {
        float w = wrow[1792 + t];
#pragma unroll
        for (int r = 0; r < 4; r++) accT[r] = fmaf(g[r], w, accT[r]);
      }
    }
#pragma unroll
    for (int r = 0; r < 4; r++) {
      float* orow = wvout + (size_t)(b0 + r) * NMK;
#pragma unroll
      for (int jj = 0; jj < 7; jj++) orow[t + 256 * jj] = acc7[jj][r];
      if (t < 144) orow[1792 + t] = accT[r];
    }
  }
}

// ---------------------------------------------------------------------------
// K2 (FUSED): gather + strength gate + windowed scatter + cell update
//             -> conv1 + conv2 + pool, all in one kernel per batch element.
// Why fused: the update phase is memory/latency-bound with ~0 MFMA; the conv
// phase is MFMA/LDS-bound. As separate dispatches they serialize stream-wide;
// fused, block i's update phase co-schedules with other blocks' conv phases
// on the same CU. ubf becomes block-private produce-then-consume (L1/L2-hot,
// ordered by __syncthreads; no cross-block dependency since conv1's halo is
// within-image and zero-padded).
// LDS ALIASING: update arrays (~19KB) live inside y1's 53,856B region; the
// update phase fully completes (barrier) before y1 takes over.
// Conv-phase structure (proven rounds 6-8):
//  - y1 RING of 6 row-slots; column halo folded into phys col 0.
//  - a1/a2 loaded per-tile with asm-opaque pointers (LICM defeat) -- round-6
//    lesson: a2 live across Phase B -> 213 MB scratch. Round-5 lesson:
//    (256,3) -> catastrophic spill. Keep (256,2) + per-phase weight lifetimes.
// ---------------------------------------------------------------------------
#define Y1ROW 4488  /* 33*136 shorts per ring slot */
__global__ __launch_bounds__(256, 2) void k_fused(
    const float* __restrict__ cell, const float* __restrict__ gaze,
    const float* __restrict__ wvin,
    const float* __restrict__ ws1, const float* __restrict__ bs1,
    const float* __restrict__ ws2, const float* __restrict__ bs2,
    float* __restrict__ updated, unsigned short* __restrict__ ubf,
    const unsigned short* __restrict__ ap1, const float* __restrict__ cb1,
    const unsigned short* __restrict__ ap2, const float* __restrict__ cb2,
    float* __restrict__ ypool) {
  __shared__ __align__(16) char smem[53856];
  unsigned short (*y1)[33][136] = (unsigned short (*)[33][136])smem;
  float* numl   = (float*)smem;            // [16][129] = 8256 B
  float* denl   = (float*)(smem + 8256);   // [128]
  float* ws1s   = (float*)(smem + 8768);   // [2048]
  float* bs1s   = (float*)(smem + 16960);  // [64]
  float* ws2s   = (float*)(smem + 17216);  // [64]
  float* nwsS   = (float*)(smem + 17472);  // [121]
  float* z2part = (float*)(smem + 17956);  // [2][128]
  float* gsum_p = (float*)(smem + 18980);  // [1]
  float* bs2_p  = (float*)(smem + 18984);  // [1]

  const int t = threadIdx.x;
  const int b = blockIdx.x;

  // ======================= PHASE U: cell update =======================
  {
    const int kk = t & 127;   // gauss point
    const int hf = t >> 7;    // j-half

    for (int e = t; e < 16 * 129; e += 256) numl[e] = 0.f;
    if (t < 128) denl[t] = 0.f;
    for (int e = t; e < 2048; e += 256) ws1s[e] = ws1[e];
    if (t < 64) { bs1s[t] = bs1[t]; ws2s[t] = ws2[t]; }
    if (t == 0) *bs2_p = bs2[0];

    const float gx = fminf(fmaxf(gaze[(size_t)b * 2 + 0] * 31.f, 0.f), 31.f);
    const float gy = fminf(fmaxf(gaze[(size_t)b * 2 + 1] * 31.f, 0.f), 31.f);
    const int x0 = (int)floorf(gx);
    const int y0 = (int)floorf(gy);
    const int wx0 = max(0, x0 - 5);
    const int wy0 = max(0, y0 - 5);

    int xi = 0, yi = 0;
    if (kk < NK) {
      int ox = kk % 11 - 5;
      int oy = kk / 11 - 5;
      xi = min(max(x0 + ox, 0), 31);
      yi = min(max(y0 + oy, 0), 31);
      if (hf == 0) {
        float dx = (float)xi - gx, dy = (float)yi - gy;
        nwsS[kk] = expf(-(dx * dx + dy * dy) * (9.0f / 242.0f));
      }
    }
    __syncthreads();
    if (t < 64) {
      float s = nwsS[t] + ((t + 64 < NK) ? nwsS[t + 64] : 0.f);
      s += __shfl_xor(s, 1, 64);
      s += __shfl_xor(s, 2, 64);
      s += __shfl_xor(s, 4, 64);
      s += __shfl_xor(s, 8, 64);
      s += __shfl_xor(s, 16, 64);
      s += __shfl_xor(s, 32, 64);
      if (t == 0) *gsum_p = fmaxf(s, 1e-8f);
    }
    __syncthreads();

    float prev[16], wvv[16];
    if (kk < NK) {
      const int idx = yi * 32 + xi;
#pragma unroll
      for (int m = 0; m < 16; m++) prev[m] = cell[(size_t)b * 16384 + m * 1024 + idx];
#pragma unroll
      for (int m = 0; m < 16; m++) wvv[m] = wvin[(size_t)b * NMK + kk * 16 + m];
      float z2p = 0.f;
      const int j0 = hf * 32;
#pragma unroll 4
      for (int j = j0; j < j0 + 32; j++) {
        float z = bs1s[j];
#pragma unroll
        for (int i = 0; i < 16; i++) z = fmaf(prev[i], ws1s[i * 64 + j], z);
#pragma unroll
        for (int i = 0; i < 16; i++) z = fmaf(wvv[i], ws1s[(16 + i) * 64 + j], z);
        z = fmaxf(z, 0.f);
        z2p = fmaf(z, ws2s[j], z2p);
      }
      z2part[hf * 128 + kk] = z2p;
    }
    __syncthreads();

    if (t < NK) {  // hf==0, kk==t: prev/wvv still live in registers
      const float nw = nwsS[t] / *gsum_p;
      const int local = (yi - wy0) * 11 + (xi - wx0);
      float z2 = *bs2_p + z2part[t] + z2part[128 + t];
      float gstr = 1.f / (1.f + expf(-z2));
      float w = nw * gstr;
      atomicAdd(&denl[local], w);
#pragma unroll
      for (int m = 0; m < 16; m++) {
        float nv = (1.f - w) * prev[m] + w * wvv[m];
        atomicAdd(&numl[m * 129 + local], w * nv);
      }
    }
    __syncthreads();

    const size_t cb = (size_t)b * 16384;

    // pass 1: f32 NCHW `updated` (required output), float4-vectorized
    {
      const int hw4 = t * 4;
      const int yy = hw4 >> 5, xx0 = hw4 & 31;
      const int wy = yy - wy0;
      float kp[4];
      int loc[4];
      bool inw[4];
#pragma unroll
      for (int c = 0; c < 4; ++c) {
        int wx = xx0 + c - wx0;
        bool in = ((unsigned)wy < 11u) && ((unsigned)wx < 11u);
        inw[c] = in;
        loc[c] = in ? wy * 11 + wx : 0;
        kp[c] = in ? 1.f - fminf(denl[loc[c]], 1.f) : 1.f;
      }
#pragma unroll 4
      for (int m = 0; m < 16; ++m) {
        float4 cv = *(const float4*)&cell[cb + m * 1024 + hw4];
        float4 ov;
        ov.x = kp[0] * cv.x + (inw[0] ? numl[m * 129 + loc[0]] : 0.f);
        ov.y = kp[1] * cv.y + (inw[1] ? numl[m * 129 + loc[1]] : 0.f);
        ov.z = kp[2] * cv.z + (inw[2] ? numl[m * 129 + loc[2]] : 0.f);
        ov.w = kp[3] * cv.w + (inw[3] ? numl[m * 129 + loc[3]] : 0.f);
        *(float4*)&updated[cb + m * 1024 + hw4] = ov;
      }
    }

    // pass 2: bf16 NHWC halo-padded ubf (consumed below by conv1)
    unsigned* ub32 = (unsigned*)ubf + (size_t)b * 9248;
    {
      const int p2 = t & 3;
      const int c0 = p2 * 4;
      const int hwb = t >> 2;
#pragma unroll 4
      for (int it = 0; it < 16; ++it) {
        const int hw = hwb + it * 64;
        const int yy = hw >> 5, xx = hw & 31;
        const int wy = yy - wy0, wx = xx - wx0;
        const bool in = ((unsigned)wy < 11u) && ((unsigned)wx < 11u);
        const int loc = in ? wy * 11 + wx : 0;
        const float kp = in ? 1.f - fminf(denl[loc], 1.f) : 1.f;
        float v0 = kp * cell[cb + (c0 + 0) * 1024 + hw] + (in ? numl[(c0 + 0) * 129 + loc] : 0.f);
        float v1 = kp * cell[cb + (c0 + 1) * 1024 + hw] + (in ? numl[(c0 + 1) * 129 + loc] : 0.f);
        float v2 = kp * cell[cb + (c0 + 2) * 1024 + hw] + (in ? numl[(c0 + 2) * 129 + loc] : 0.f);
        float v3 = kp * cell[cb + (c0 + 3) * 1024 + hw] + (in ? numl[(c0 + 3) * 129 + loc] : 0.f);
        uint2 pk;
        pk.x = cvtpk(v0, v1);
        pk.y = cvtpk(v2, v3);
        *(uint2*)(ub32 + ((size_t)((yy + 1) * 34 + (xx + 1)) * 8 + p2 * 2)) = pk;
      }
    }
    // zero halo (132 border cells x 16 ci)
    for (int e = t; e < 1056; e += 256) {
      int j = e & 7, pos = e >> 3;
      int row, col;
      if (pos < 34)       { row = 0;             col = pos; }
      else if (pos < 68)  { row = 33;            col = pos - 34; }
      else if (pos < 100) { row = pos - 68 + 1;  col = 0; }
      else                { row = pos - 100 + 1; col = 33; }
      ub32[(row * 34 + col) * 8 + j] = 0u;
    }
  }
  // barrier: update arrays (LDS) dead; ubf global writes visible block-wide
  __syncthreads();

  // ======================= PHASE C: conv1+conv2+pool =======================
  const int lane = t & 63;
  const int w = t >> 6;        // wave 0..3
  const int ln = lane & 15;
  const int q = lane >> 4;
  const int qh = q >> 1, ql = q & 1;

  const unsigned short* ubb = ubf + (size_t)b * 18496;
  const unsigned short* ap2w = ap2 + (size_t)(w * 36 * 64 + lane) * 8;
  const unsigned short* ap1w = ap1 + (size_t)(w * 10 * 64 + lane) * 8;

  f32x4 cb2r;
  {
    int c2b = w * 16 + q * 4;
    cb2r = f32x4{cb2[c2b], cb2[c2b + 1], cb2[c2b + 2], cb2[c2b + 3]};
  }
  f32x4 cb1r[2];
#pragma unroll
  for (int m2 = 0; m2 < 2; m2++) {
    int c1b = w * 32 + m2 * 16 + q * 4;
    cb1r[m2] = f32x4{cb1[c1b], cb1[c1b + 1], cb1[c1b + 2], cb1[c1b + 3]};
  }

  // per-lane conv1 tap offsets. s==9 -> clamp to 0: ap1 holds A=0 there.
  int po1[5];
#pragma unroll
  for (int kc = 0; kc < 5; kc++) {
    int s = 2 * kc + qh;
    if (s > 8) s = 0;
    po1[kc] = (s / 3) * 544 + (s % 3) * 16;
  }

  // zero the shared halo column (phys col 0 of each ring slot)
  for (int e = t; e < 6 * 68; e += 256) {
    int s = e / 68, wd = e % 68;
    ((unsigned*)y1)[s * (Y1ROW / 2) + wd] = 0u;
  }

  // pool accumulators: [row-bucket] x {h=0 (cols 0-15), h=1 (cols 16-31)}
  f32x4 PL0 = {0.f, 0.f, 0.f, 0.f}, PL1 = PL0, PL2 = PL0;
  f32x4 PH0 = PL0, PH1 = PL0, PH2 = PL0;

#pragma unroll 1
  for (int ti = 0; ti < 8; ti++) {
    const int r0 = ti * 4;

    // Opaque pointer copies: defeat LICM so a1/a2 loads stay per-tile.
    const unsigned short* p1 = ap1w;
    const unsigned short* p2 = ap2w;
    asm volatile("" : "+v"(p1), "+v"(p2));

    // conv1 weights: live only during Phase B
    bf16x8 a1[5][2];
#pragma unroll
    for (int kc = 0; kc < 5; kc++)
#pragma unroll
      for (int m2 = 0; m2 < 2; m2++)
        a1[kc][m2] = *(const bf16x8*)(p1 + (size_t)((kc * 2 + m2) * 64) * 8);

    // ---- Phase B: conv1 for NEW rows only (ring). ti=0: abs rows -1..4;
    //      else abs rows r0+1..r0+4. Slot(r) = (r+1) % 6. ----
    const int nrow = (ti == 0) ? 6 : 4;
    const int abase = (ti == 0) ? -1 : r0 + 1;
#pragma unroll 2
    for (int nt = 0; nt < nrow * 2; nt++) {
      const int ry = nt >> 1, h = nt & 1;
      const int gy1 = abase + ry;
      const int slot = (gy1 + 1) % 6;
      const int gyc = min(max(gy1, 0), 31);  // in-bounds reads; result masked
      const int x = h * 16 + ln;
      const unsigned short* bp = ubb + gyc * 544 + x * 16 + ql * 8;
      bf16x8 f0 = *(const bf16x8*)(bp + po1[0]);
      bf16x8 f1 = *(const bf16x8*)(bp + po1[1]);
      bf16x8 f2 = *(const bf16x8*)(bp + po1[2]);
      bf16x8 f3 = *(const bf16x8*)(bp + po1[3]);
      bf16x8 f4 = *(const bf16x8*)(bp + po1[4]);
      f32x4 acc0 = cb1r[0], acc1 = cb1r[1];
      acc0 = MFMA(a1[0][0], f0, acc0, 0, 0, 0); acc1 = MFMA(a1[0][1], f0, acc1, 0, 0, 0);
      acc0 = MFMA(a1[1][0], f1, acc0, 0, 0, 0); acc1 = MFMA(a1[1][1], f1, acc1, 0, 0, 0);
      acc0 = MFMA(a1[2][0], f2, acc0, 0, 0, 0); acc1 = MFMA(a1[2][1], f2, acc1, 0, 0, 0);
      acc0 = MFMA(a1[3][0], f3, acc0, 0, 0, 0); acc1 = MFMA(a1[3][1], f3, acc1, 0, 0, 0);
      acc0 = MFMA(a1[4][0], f4, acc0, 0, 0, 0); acc1 = MFMA(a1[4][1], f4, acc1, 0, 0, 0);
      const bool inr = ((unsigned)gy1 < 32u);
#pragma unroll
      for (int m2 = 0; m2 < 2; m2++) {
        f32x4 a = m2 ? acc1 : acc0;
        float v0 = inr ? fmaxf(a[0], 0.f) : 0.f;
        float v1 = inr ? fmaxf(a[1], 0.f) : 0.f;
        float v2 = inr ? fmaxf(a[2], 0.f) : 0.f;
        float v3 = inr ? fmaxf(a[3], 0.f) : 0.f;
        uint2 pk;
        pk.x = cvtpk(v0, v1);
        pk.y = cvtpk(v2, v3);
        *(uint2*)&y1[slot][1 + x][w * 32 + m2 * 16 + q * 4] = pk;
      }
    }

    // conv2 weights: issued after Phase B, live only during Phase C.
    bf16x8 a2[9][4];
#pragma unroll
    for (int s = 0; s < 9; s++)
#pragma unroll
      for (int kc = 0; kc < 4; kc++)
        a2[s][kc] = *(const bf16x8*)(p2 + (size_t)((s * 4 + kc) * 64) * 8);

    __syncthreads();

    // ---- Phase C: conv2 rows r0..r0+3 from the 6 ring slots ----
    int rowoff[6];
    {
      int s0 = (r0) % 6;
#pragma unroll
      for (int yr = 0; yr < 6; yr++) {
        int s = s0 + yr;
        if (s >= 6) s -= 6;
        rowoff[yr] = s * Y1ROW;
      }
    }
    __builtin_amdgcn_s_setprio(1);
#pragma unroll
    for (int h = 0; h < 2; h++) {
      const int xg = h * 16 + ln;
      const unsigned short* rp[6];
#pragma unroll
      for (int yr = 0; yr < 6; yr++) rp[yr] = &y1[0][0][0] + rowoff[yr] + q * 8;
      int pco[3];
#pragma unroll
      for (int dx = 0; dx < 3; dx++) {
        int pc = xg + dx;            // phys col; 33 wraps to shared zero col 0
        if (pc == 33) pc = 0;
        pco[dx] = pc * 136;
      }
      f32x4 A0 = cb2r, A1 = cb2r, A2 = cb2r, A3 = cb2r;
#pragma unroll
      for (int yr = 0; yr < 6; yr++)
#pragma unroll
        for (int kc = 0; kc < 4; kc++)
#pragma unroll
          for (int dx = 0; dx < 3; dx++) {
            bf16x8 fr = *(const bf16x8*)(rp[yr] + pco[dx] + kc * 32);
#pragma unroll
            for (int dy = 0; dy < 3; dy++) {
              const int rr = yr - dy;
              if (rr < 0 || rr > 3) continue;
              f32x4& ac = (rr == 0) ? A0 : ((rr == 1) ? A1 : ((rr == 2) ? A2 : A3));
              ac = MFMA(a2[dy * 3 + dx][kc], fr, ac, 0, 0, 0);
            }
          }
#pragma unroll
      for (int rr = 0; rr < 4; rr++) {
        const int grow = r0 + rr;
        const float rm0 = (grow <= 10) ? 1.f : 0.f;
        const float rm1 = (grow >= 10 && grow <= 21) ? 1.f : 0.f;
        const float rm2 = (grow >= 21) ? 1.f : 0.f;
        f32x4 v = (rr == 0) ? A0 : ((rr == 1) ? A1 : ((rr == 2) ? A2 : A3));
        v[0] = fmaxf(v[0], 0.f);
        v[1] = fmaxf(v[1], 0.f);
        v[2] = fmaxf(v[2], 0.f);
        v[3] = fmaxf(v[3], 0.f);
        if (h == 0) {
          PL0 += v * rm0; PL1 += v * rm1; PL2 += v * rm2;
        } else {
          PH0 += v * rm0; PH1 += v * rm1; PH2 += v * rm2;
        }
      }
    }
    __builtin_amdgcn_s_setprio(0);
    __syncthreads();
  }

  // ---- final pool: col masks + one 16-lane butterfly + direct stores ----
  const float mA0 = (ln <= 10) ? 1.f : 0.f;
  const float mA1 = (ln >= 10) ? 1.f : 0.f;
  const float mB1 = (ln <= 5) ? 1.f : 0.f;
  const float mB2 = (ln >= 5) ? 1.f : 0.f;
  f32x4 t00 = PL0 * mA0, t01 = PL0 * mA1 + PH0 * mB1, t02 = PH0 * mB2;
  f32x4 t10 = PL1 * mA0, t11 = PL1 * mA1 + PH1 * mB1, t12 = PH1 * mB2;
  f32x4 t20 = PL2 * mA0, t21 = PL2 * mA1 + PH2 * mB1, t22 = PH2 * mB2;

  {
    f32x4* tv[9] = {&t00, &t01, &t02, &t10, &t11, &t12, &t20, &t21, &t22};
#pragma unroll
    for (int i = 0; i < 9; i++) {
      f32x4& v = *tv[i];
#pragma unroll
      for (int c = 0; c < 4; c++) {
        float s = v[c];
        s += __shfl_xor(s, 1, 64);
        s += __shfl_xor(s, 2, 64);
        s += __shfl_xor(s, 4, 64);
        s += __shfl_xor(s, 8, 64);
        v[c] = s;
      }
    }
  }

  float* yp = ypool + (size_t)b * 576 + (w * 16 + q * 4) * 9;
#define PWRITE(tv, ph, pw)                                                      \
  if (ln == (ph * 3 + pw)) {                                                    \
    const float dv = 1.f / (float)(((ph == 1) ? 12 : 11) * ((pw == 1) ? 12 : 11)); \
    yp[0 * 9 + ph * 3 + pw] = tv[0] * dv;                                       \
    yp[1 * 9 + ph * 3 + pw] = tv[1] * dv;                                       \
    yp[2 * 9 + ph * 3 + pw] = tv[2] * dv;                                       \
    yp[3 * 9 + ph * 3 + pw] = tv[3] * dv;                                       \
  }
  PWRITE(t00, 0, 0) PWRITE(t01, 0, 1) PWRITE(t02, 0, 2)
  PWRITE(t10, 1, 0) PWRITE(t11, 1, 1) PWRITE(t12, 1, 2)
  PWRITE(t20, 2, 0) PWRITE(t21, 2, 1) PWRITE(t22, 2, 2)
#undef PWRITE
}

// ---------------------------------------------------------------------------
// K4: out = ypool @ wo + bo.  4 rows/block (512 blocks = 2/CU), 3 jj-streams.
// ---------------------------------------------------------------------------
__global__ __launch_bounds__(256) void k_out(
    const float* __restrict__ ypool, const float* __restrict__ wo,
    const float* __restrict__ bo, float* __restrict__ out) {
  __shared__ float ys[4][576];
  const int t = threadIdx.x;
  const int b0 = blockIdx.x * 4;
  for (int e = t; e < 4 * 576; e += 256) {
    int r = e / 576, i = e % 576;
    ys[r][i] = ypool[(size_t)(b0 + r) * 576 + i];
  }
  __syncthreads();
  float a0[4], a1[4], aT[4];
  {
    float bb0 = bo[t], bb1 = bo[t + 256];
    float bbT = (t < 64) ? bo[512 + t] : 0.f;
#pragma unroll
    for (int r = 0; r < 4; r++) { a0[r] = bb0; a1[r] = bb1; aT[r] = bbT; }
  }
#pragma unroll 2
  for (int i = 0; i < 576; i++) {
    const float* wr = wo + (size_t)i * 576;
    float w0 = wr[t], w1 = wr[t + 256];
    float g[4];
#pragma unroll
    for (int r = 0; r < 4; r++) g[r] = ys[r][i];
#pragma unroll
    for (int r = 0; r < 4; r++) {
      a0[r] = fmaf(g[r], w0, a0[r]);
      a1[r] = fmaf(g[r], w1, a1[r]);
    }
    if (t < 64) {  // wave 0 only: uniform, no divergence inside a wave
      float wT = wr[512 + t];
#pragma unroll
      for (int r = 0; r < 4; r++) aT[r] = fmaf(g[r], wT, aT[r]);
    }
  }
#pragma unroll
  for (int r = 0; r < 4; r++) {
    float* orow = out + (size_t)(b0 + r) * 576;
    orow[t] = a0[r];
    orow[t + 256] = a1[r];
    if (t < 64) orow[512 + t] = aT[r];
  }
}

extern "C" void kernel_launch(void* const* d_in, const int* in_sizes, int n_in,
                              void* d_out, int out_size, void* d_ws, size_t ws_size,
                              hipStream_t stream) {
  (void)in_sizes; (void)n_in; (void)out_size; (void)ws_size;
  const float* feat = (const float*)d_in[0];
  const float* cell = (const float*)d_in[1];
  const float* gaze = (const float*)d_in[2];
  const float* w1   = (const float*)d_in[3];
  const float* b1   = (const float*)d_in[4];
  const float* w2   = (const float*)d_in[5];
  const float* b2   = (const float*)d_in[6];
  const float* wv   = (const float*)d_in[7];
  const float* bv   = (const float*)d_in[8];
  const float* ws1  = (const float*)d_in[9];
  const float* bs1  = (const float*)d_in[10];
  const float* ws2  = (const float*)d_in[11];
  const float* bs2  = (const float*)d_in[12];
  const float* ck1  = (const float*)d_in[13];
  const float* cb1  = (const float*)d_in[14];
  const float* ck2  = (const float*)d_in[15];
  const float* cb2  = (const float*)d_in[16];
  const float* wo   = (const float*)d_in[17];
  const float* bo   = (const float*)d_in[18];

  float* out0    = (float*)d_out;                    // (B,576)
  float* updated = out0 + (size_t)NB * 576;          // (B,16,32,32)
  float* wvout   = (float*)d_ws;                     // B*1936 f32
  float* ypool   = wvout + (size_t)NB * NMK;         // B*576 f32
  unsigned short* ap1 = (unsigned short*)(ypool + (size_t)NB * 576);  // 20480 bf16
  unsigned short* ap2 = ap1 + 20480;                                  // 73728 bf16
  unsigned short* ubf = ap2 + 73728;  // NB*34*34*16 bf16 (block-private scratch)
  // peak ws = 20.8 MB fixed + 75.8 MB ubf = 96.6 MB (proven rounds 6-8)

  k_pack<<<dim3(368), dim3(256), 0, stream>>>(ck1, ck2, ap1, ap2);
  k_mlp<<<dim3(NB / 4), dim3(256), 0, stream>>>(feat, gaze, w1, b1, w2, b2, wv, bv, wvout);
  k_fused<<<dim3(NB), dim3(256), 0, stream>>>(
      cell, gaze, wvout, ws1, bs1, ws2, bs2, updated, ubf,
      ap1, cb1, ap2, cb2, ypool);
  k_out<<<dim3(NB / 8 * 2), dim3(256), 0, stream>>>(ypool, wo, bo, out0);
}

// Round 10
// 1087.993 us; speedup vs baseline: 1.0769x; 1.0769x over previous
//
#include <hip/hip_runtime.h>
#include <hip/hip_bf16.h>
#include <math.h>

#define NB 2048
#define NF 512
#define NM 16
#define NK 121
#define NMK 1936

typedef __attribute__((ext_vector_type(8))) short bf16x8;
typedef __attribute__((ext_vector_type(4))) float f32x4;

#define MFMA __builtin_amdgcn_mfma_f32_16x16x32_bf16

static __device__ __forceinline__ unsigned short f2b(float f) {
  unsigned int u = __float_as_uint(f);
  unsigned int lsb = (u >> 16) & 1u;
  u += 0x7fffu + lsb;
  return (unsigned short)(u >> 16);
}

// pack two f32 -> one dword of 2x bf16 (RNE), low = lo
static __device__ __forceinline__ unsigned cvtpk(float lo, float hi) {
  unsigned r;
  asm("v_cvt_pk_bf16_f32 %0, %1, %2" : "=v"(r) : "v"(lo), "v"(hi));
  return r;
}

// ---------------------------------------------------------------------------
// K0: pre-pack conv weights into per-wave MFMA A-fragment slices (bf16).
// ap1: [w(4)][kc(5)][m2(2)][lane(64)][j(8)]  -- wave w owns c1 in [32w,32w+32)
// ap2: [mt(4)][s(9)][kc(4)][lane(64)][j(8)]  -- wave mt owns c2 in [16mt,16mt+16)
// A[m][k]: m = lane&15, k = (lane>>4)*8 + j  (16x16x32 A-operand layout).
// NOTE: ap1 stores ZERO for s==9 (tail of padded K=160) -- k_conv3 relies on
// this to skip B-fragment masking for the invalid tap.
// ---------------------------------------------------------------------------
__global__ __launch_bounds__(256) void k_pack(
    const float* __restrict__ ck1, const float* __restrict__ ck2,
    unsigned short* __restrict__ ap1, unsigned short* __restrict__ ap2) {
  int i = blockIdx.x * 256 + threadIdx.x;
  if (i < 20480) {
    int j = i & 7, lane = (i >> 3) & 63;
    int m2 = (i >> 9) & 1, kc = (i >> 10) % 5, w = i / 5120;
    int c1 = w * 32 + m2 * 16 + (lane & 15);
    int k = kc * 32 + ((lane >> 4) << 3) + j;
    int s = k >> 4, ci = k & 15;
    float v = 0.f;
    if (s < 9) v = ck1[((c1 * 16 + ci) * 3 + s / 3) * 3 + (s % 3)];
    ap1[i] = f2b(v);
  }
  int i2 = i - 20480;
  if (i2 >= 0 && i2 < 73728) {
    int j = i2 & 7, lane = (i2 >> 3) & 63;
    int kc = (i2 >> 9) & 3, s = (i2 >> 11) % 9, mt = i2 / 18432;
    int c2 = mt * 16 + (lane & 15);
    int c1 = kc * 32 + ((lane >> 4) << 3) + j;
    float v = ck2[((c2 * 128 + c1) * 3 + s / 3) * 3 + (s % 3)];
    ap2[i2] = f2b(v);
  }
}

// ---------------------------------------------------------------------------
// K1: MLP  x=[features|pos_enc] (576) -> 256 -> 128 -> 1936 write_vals
// 2 rows/block (1024 blocks = 4 blocks/CU, 16 waves/CU): doubled occupancy
// vs round-8's 4-row version -- these dependent-load GEMV loops are latency
// bound, not BW bound (weights are L2-hit).
// ---------------------------------------------------------------------------
__global__ __launch_bounds__(256) void k_mlp(
    const float* __restrict__ feat, const float* __restrict__ gaze,
    const float* __restrict__ w1, const float* __restrict__ b1,
    const float* __restrict__ w2, const float* __restrict__ b2,
    const float* __restrict__ wv, const float* __restrict__ bv,
    float* __restrict__ wvout) {
  __shared__ float xs[2][576];
  __shared__ float g1[2][256];
  __shared__ float g2[2][128];
  const int t = threadIdx.x;
  const int b0 = blockIdx.x * 2;

  for (int e = t; e < 2 * 512; e += 256) {
    int r = e >> 9, i = e & 511;
    xs[r][i] = feat[(size_t)(b0 + r) * NF + i];
  }
  if (t < 2 * 64) {
    int r = t >> 6, i = t & 63;
    int axis = i >> 5;
    int ii = i & 31;
    int jj = ii >> 1;
    int isc = ii & 1;
    float p = gaze[(size_t)(b0 + r) * 2 + axis];
    float dv = expf(-(float)(2 * jj) * 0.28782313662425575f);
    float ang = p * dv;
    xs[r][512 + i] = isc ? cosf(ang) : sinf(ang);
  }
  __syncthreads();
  {
    float acc[2];
    float bb = b1[t];
#pragma unroll
    for (int r = 0; r < 2; r++) acc[r] = bb;
#pragma unroll 8
    for (int i = 0; i < 576; i++) {
      float w = w1[(size_t)i * 256 + t];
#pragma unroll
      for (int r = 0; r < 2; r++) acc[r] = fmaf(xs[r][i], w, acc[r]);
    }
#pragma unroll
    for (int r = 0; r < 2; r++) g1[r][t] = fmaxf(acc[r], 0.f);
  }
  __syncthreads();
  if (t < 128) {
    float acc[2];
    float bb = b2[t];
#pragma unroll
    for (int r = 0; r < 2; r++) acc[r] = bb;
#pragma unroll 8
    for (int i = 0; i < 256; i++) {
      float w = w2[(size_t)i * 128 + t];
#pragma unroll
      for (int r = 0; r < 2; r++) acc[r] = fmaf(g1[r][i], w, acc[r]);
    }
#pragma unroll
    for (int r = 0; r < 2; r++) g2[r][t] = fmaxf(acc[r], 0.f);
  }
  __syncthreads();
  {
    float acc7[7][2];  // j = t + 256*jj, jj<7 (j <= 1791, always valid)
    float accT[2];     // j = 1792 + t, valid for t < 144
#pragma unroll
    for (int jj = 0; jj < 7; jj++) {
      float bb = bv[t + 256 * jj];
#pragma unroll
      for (int r = 0; r < 2; r++) acc7[jj][r] = bb;
    }
    {
      float bb = (t < 144) ? bv[1792 + t] : 0.f;
#pragma unroll
      for (int r = 0; r < 2; r++) accT[r] = bb;
    }
#pragma unroll 2
    for (int i = 0; i < 128; i++) {
      float g[2];
#pragma unroll
      for (int r = 0; r < 2; r++) g[r] = g2[r][i];
      const float* wrow = wv + (size_t)i * NMK;
#pragma unroll
      for (int jj = 0; jj < 7; jj++) {
        float w = wrow[t + 256 * jj];
#pragma unroll
        for (int r = 0; r < 2; r++) acc7[jj][r] = fmaf(g[r], w, acc7[jj][r]);
      }
      if (t < 144) {
        float w = wrow[1792 + t];
#pragma unroll
        for (int r = 0; r < 2; r++) accT[r] = fmaf(g[r], w, accT[r]);
      }
    }
#pragma unroll
    for (int r = 0; r < 2; r++) {
      float* orow = wvout + (size_t)(b0 + r) * NMK;
#pragma unroll
      for (int jj = 0; jj < 7; jj++) orow[t + 256 * jj] = acc7[jj][r];
      if (t < 144) orow[1792 + t] = accT[r];
    }
  }
}

// ---------------------------------------------------------------------------
// K2: gather + strength gate + windowed scatter + cell update.
// (round-8 proven version: vectorized output passes, ~8 blocks/CU, ~110 us)
// ---------------------------------------------------------------------------
__global__ __launch_bounds__(256) void k_update(
    const float* __restrict__ cell, const float* __restrict__ gaze,
    const float* __restrict__ wvin,
    const float* __restrict__ ws1, const float* __restrict__ bs1,
    const float* __restrict__ ws2, const float* __restrict__ bs2,
    float* __restrict__ updated, unsigned short* __restrict__ ubf) {
  __shared__ float numl[16][129];  // +1 pad: de-conflict paired reads
  __shared__ float denl[128];
  __shared__ float ws1s[2048];
  __shared__ float bs1s[64];
  __shared__ float ws2s[64];
  __shared__ float nws[121];
  __shared__ float z2part[2][128];
  __shared__ float gsum_s;
  __shared__ float bs2s;
  const int t = threadIdx.x;
  const int b = blockIdx.x;
  const int kk = t & 127;   // gauss point
  const int hf = t >> 7;    // j-half

  for (int e = t; e < 16 * 129; e += 256) ((float*)numl)[e] = 0.f;
  if (t < 128) denl[t] = 0.f;
  for (int e = t; e < 2048; e += 256) ws1s[e] = ws1[e];
  if (t < 64) { bs1s[t] = bs1[t]; ws2s[t] = ws2[t]; }
  if (t == 0) bs2s = bs2[0];

  const float gx = fminf(fmaxf(gaze[(size_t)b * 2 + 0] * 31.f, 0.f), 31.f);
  const float gy = fminf(fmaxf(gaze[(size_t)b * 2 + 1] * 31.f, 0.f), 31.f);
  const int x0 = (int)floorf(gx);
  const int y0 = (int)floorf(gy);
  const int wx0 = max(0, x0 - 5);
  const int wy0 = max(0, y0 - 5);

  int xi = 0, yi = 0;
  if (kk < NK) {
    int ox = kk % 11 - 5;
    int oy = kk / 11 - 5;
    xi = min(max(x0 + ox, 0), 31);
    yi = min(max(y0 + oy, 0), 31);
    if (hf == 0) {
      float dx = (float)xi - gx, dy = (float)yi - gy;
      nws[kk] = expf(-(dx * dx + dy * dy) * (9.0f / 242.0f));
    }
  }
  __syncthreads();
  if (t < 64) {
    float s = nws[t] + ((t + 64 < NK) ? nws[t + 64] : 0.f);
    s += __shfl_xor(s, 1, 64);
    s += __shfl_xor(s, 2, 64);
    s += __shfl_xor(s, 4, 64);
    s += __shfl_xor(s, 8, 64);
    s += __shfl_xor(s, 16, 64);
    s += __shfl_xor(s, 32, 64);
    if (t == 0) gsum_s = fmaxf(s, 1e-8f);
  }
  __syncthreads();

  float prev[16], wvv[16];
  if (kk < NK) {
    const int idx = yi * 32 + xi;
#pragma unroll
    for (int m = 0; m < 16; m++) prev[m] = cell[(size_t)b * 16384 + m * 1024 + idx];
#pragma unroll
    for (int m = 0; m < 16; m++) wvv[m] = wvin[(size_t)b * NMK + kk * 16 + m];
    float z2p = 0.f;
    const int j0 = hf * 32;
#pragma unroll 4
    for (int j = j0; j < j0 + 32; j++) {
      float z = bs1s[j];
#pragma unroll
      for (int i = 0; i < 16; i++) z = fmaf(prev[i], ws1s[i * 64 + j], z);
#pragma unroll
      for (int i = 0; i < 16; i++) z = fmaf(wvv[i], ws1s[(16 + i) * 64 + j], z);
      z = fmaxf(z, 0.f);
      z2p = fmaf(z, ws2s[j], z2p);
    }
    z2part[hf][kk] = z2p;
  }
  __syncthreads();

  if (t < NK) {  // hf==0, kk==t: prev/wvv still live in registers
    const float nw = nws[t] / gsum_s;
    const int local = (yi - wy0) * 11 + (xi - wx0);
    float z2 = bs2s + z2part[0][t] + z2part[1][t];
    float gstr = 1.f / (1.f + expf(-z2));
    float w = nw * gstr;
    atomicAdd(&denl[local], w);
#pragma unroll
    for (int m = 0; m < 16; m++) {
      float nv = (1.f - w) * prev[m] + w * wvv[m];
      atomicAdd(&numl[m][local], w * nv);
    }
  }
  __syncthreads();

  const size_t cb = (size_t)b * 16384;

  // ---- pass 1: f32 NCHW output, float4-vectorized ----
  {
    const int hw4 = t * 4;
    const int yy = hw4 >> 5, xx0 = hw4 & 31;
    const int wy = yy - wy0;
    float kp[4];
    int loc[4];
    bool inw[4];
#pragma unroll
    for (int c = 0; c < 4; ++c) {
      int wx = xx0 + c - wx0;
      bool in = ((unsigned)wy < 11u) && ((unsigned)wx < 11u);
      inw[c] = in;
      loc[c] = in ? wy * 11 + wx : 0;
      kp[c] = in ? 1.f - fminf(denl[loc[c]], 1.f) : 1.f;
    }
#pragma unroll 4
    for (int m = 0; m < 16; ++m) {
      float4 cv = *(const float4*)&cell[cb + m * 1024 + hw4];
      float4 ov;
      ov.x = kp[0] * cv.x + (inw[0] ? numl[m][loc[0]] : 0.f);
      ov.y = kp[1] * cv.y + (inw[1] ? numl[m][loc[1]] : 0.f);
      ov.z = kp[2] * cv.z + (inw[2] ? numl[m][loc[2]] : 0.f);
      ov.w = kp[3] * cv.w + (inw[3] ? numl[m][loc[3]] : 0.f);
      *(float4*)&updated[cb + m * 1024 + hw4] = ov;
    }
  }

  // ---- pass 2: bf16 NHWC halo-padded ubf, 4 channels per thread ----
  unsigned* ub32 = (unsigned*)ubf + (size_t)b * 9248;  // 18496 shorts / 2
  {
    const int p2 = t & 3;
    const int c0 = p2 * 4;
    const int hwb = t >> 2;
#pragma unroll 4
    for (int it = 0; it < 16; ++it) {
      const int hw = hwb + it * 64;
      const int yy = hw >> 5, xx = hw & 31;
      const int wy = yy - wy0, wx = xx - wx0;
      const bool in = ((unsigned)wy < 11u) && ((unsigned)wx < 11u);
      const int loc = in ? wy * 11 + wx : 0;
      const float kp = in ? 1.f - fminf(denl[loc], 1.f) : 1.f;
      float v0 = kp * cell[cb + (c0 + 0) * 1024 + hw] + (in ? numl[c0 + 0][loc] : 0.f);
      float v1 = kp * cell[cb + (c0 + 1) * 1024 + hw] + (in ? numl[c0 + 1][loc] : 0.f);
      float v2 = kp * cell[cb + (c0 + 2) * 1024 + hw] + (in ? numl[c0 + 2][loc] : 0.f);
      float v3 = kp * cell[cb + (c0 + 3) * 1024 + hw] + (in ? numl[c0 + 3][loc] : 0.f);
      uint2 pk;
      pk.x = cvtpk(v0, v1);
      pk.y = cvtpk(v2, v3);
      *(uint2*)(ub32 + ((size_t)((yy + 1) * 34 + (xx + 1)) * 8 + p2 * 2)) = pk;
    }
  }

  // zero halo (132 border cells x 16 ci); rewritten every launch
  for (int e = t; e < 1056; e += 256) {
    int j = e & 7, pos = e >> 3;
    int row, col;
    if (pos < 34)       { row = 0;             col = pos; }
    else if (pos < 68)  { row = 33;            col = pos - 34; }
    else if (pos < 100) { row = pos - 68 + 1;  col = 0; }
    else                { row = pos - 100 + 1; col = 33; }
    ub32[(row * 34 + col) * 8 + j] = 0u;
  }
}

// ---------------------------------------------------------------------------
// K3: MFMA conv1+conv2+pool.  (round-8 proven version)
//  - y1 RING of 6 row-slots; column halo folded into phys col 0 (53,856 B).
//  - a1/a2 per-tile lifetimes + asm-opaque LICM defeat (round-6 lesson:
//    a2 live across Phase B -> 213 MB scratch; round-5: (256,3) -> 5 GB).
//  - s_setprio(1) around Phase C MFMA cluster.
// ---------------------------------------------------------------------------
#define Y1ROW 4488  /* 33*136 shorts per ring slot */
__global__ __launch_bounds__(256, 2) void k_conv3(
    const unsigned short* __restrict__ ubf,
    const unsigned short* __restrict__ ap1, const float* __restrict__ cb1,
    const unsigned short* __restrict__ ap2, const float* __restrict__ cb2,
    float* __restrict__ ypool) {
  __shared__ unsigned short y1[6][33][136];
  const int t = threadIdx.x;
  const int b = blockIdx.x;
  const int lane = t & 63;
  const int w = t >> 6;        // wave 0..3
  const int ln = lane & 15;
  const int q = lane >> 4;
  const int qh = q >> 1, ql = q & 1;

  const unsigned short* ubb = ubf + (size_t)b * 18496;
  const unsigned short* ap2w = ap2 + (size_t)(w * 36 * 64 + lane) * 8;
  const unsigned short* ap1w = ap1 + (size_t)(w * 10 * 64 + lane) * 8;

  f32x4 cb2r;
  {
    int c2b = w * 16 + q * 4;
    cb2r = f32x4{cb2[c2b], cb2[c2b + 1], cb2[c2b + 2], cb2[c2b + 3]};
  }
  f32x4 cb1r[2];
#pragma unroll
  for (int m2 = 0; m2 < 2; m2++) {
    int c1b = w * 32 + m2 * 16 + q * 4;
    cb1r[m2] = f32x4{cb1[c1b], cb1[c1b + 1], cb1[c1b + 2], cb1[c1b + 3]};
  }

  // per-lane conv1 tap offsets. s==9 -> clamp to 0: ap1 holds A=0 there.
  int po1[5];
#pragma unroll
  for (int kc = 0; kc < 5; kc++) {
    int s = 2 * kc + qh;
    if (s > 8) s = 0;
    po1[kc] = (s / 3) * 544 + (s % 3) * 16;
  }

  // zero the shared halo column (phys col 0 of each ring slot), once
  for (int e = t; e < 6 * 68; e += 256) {
    int s = e / 68, wd = e % 68;
    ((unsigned*)y1)[s * (Y1ROW / 2) + wd] = 0u;
  }

  // pool accumulators: [row-bucket] x {h=0 (cols 0-15), h=1 (cols 16-31)}
  f32x4 PL0 = {0.f, 0.f, 0.f, 0.f}, PL1 = PL0, PL2 = PL0;
  f32x4 PH0 = PL0, PH1 = PL0, PH2 = PL0;

#pragma unroll 1
  for (int ti = 0; ti < 8; ti++) {
    const int r0 = ti * 4;

    // Opaque copies of the weight base pointers: defeats LICM so the a1/a2
    // loads stay INSIDE the tile loop (per-tile live ranges, no spill).
    const unsigned short* p1 = ap1w;
    const unsigned short* p2 = ap2w;
    asm volatile("" : "+v"(p1), "+v"(p2));

    // conv1 weights: live only during Phase B
    bf16x8 a1[5][2];
#pragma unroll
    for (int kc = 0; kc < 5; kc++)
#pragma unroll
      for (int m2 = 0; m2 < 2; m2++)
        a1[kc][m2] = *(const bf16x8*)(p1 + (size_t)((kc * 2 + m2) * 64) * 8);

    // ---- Phase B: conv1 for NEW rows only (ring). ti=0: abs rows -1..4;
    //      else abs rows r0+1..r0+4. Slot(r) = (r+1) % 6. ----
    const int nrow = (ti == 0) ? 6 : 4;
    const int abase = (ti == 0) ? -1 : r0 + 1;
#pragma unroll 2
    for (int nt = 0; nt < nrow * 2; nt++) {
      const int ry = nt >> 1, h = nt & 1;
      const int gy1 = abase + ry;
      const int slot = (gy1 + 1) % 6;
      const int gyc = min(max(gy1, 0), 31);  // in-bounds reads; result masked
      const int x = h * 16 + ln;
      const unsigned short* bp = ubb + gyc * 544 + x * 16 + ql * 8;
      bf16x8 f0 = *(const bf16x8*)(bp + po1[0]);
      bf16x8 f1 = *(const bf16x8*)(bp + po1[1]);
      bf16x8 f2 = *(const bf16x8*)(bp + po1[2]);
      bf16x8 f3 = *(const bf16x8*)(bp + po1[3]);
      bf16x8 f4 = *(const bf16x8*)(bp + po1[4]);
      f32x4 acc0 = cb1r[0], acc1 = cb1r[1];
      acc0 = MFMA(a1[0][0], f0, acc0, 0, 0, 0); acc1 = MFMA(a1[0][1], f0, acc1, 0, 0, 0);
      acc0 = MFMA(a1[1][0], f1, acc0, 0, 0, 0); acc1 = MFMA(a1[1][1], f1, acc1, 0, 0, 0);
      acc0 = MFMA(a1[2][0], f2, acc0, 0, 0, 0); acc1 = MFMA(a1[2][1], f2, acc1, 0, 0, 0);
      acc0 = MFMA(a1[3][0], f3, acc0, 0, 0, 0); acc1 = MFMA(a1[3][1], f3, acc1, 0, 0, 0);
      acc0 = MFMA(a1[4][0], f4, acc0, 0, 0, 0); acc1 = MFMA(a1[4][1], f4, acc1, 0, 0, 0);
      const bool inr = ((unsigned)gy1 < 32u);
#pragma unroll
      for (int m2 = 0; m2 < 2; m2++) {
        f32x4 a = m2 ? acc1 : acc0;
        float v0 = inr ? fmaxf(a[0], 0.f) : 0.f;
        float v1 = inr ? fmaxf(a[1], 0.f) : 0.f;
        float v2 = inr ? fmaxf(a[2], 0.f) : 0.f;
        float v3 = inr ? fmaxf(a[3], 0.f) : 0.f;
        uint2 pk;
        pk.x = cvtpk(v0, v1);
        pk.y = cvtpk(v2, v3);
        *(uint2*)&y1[slot][1 + x][w * 32 + m2 * 16 + q * 4] = pk;
      }
    }

    // conv2 weights: issued after Phase B (latency overlaps the barrier),
    // live only during Phase C.
    bf16x8 a2[9][4];
#pragma unroll
    for (int s = 0; s < 9; s++)
#pragma unroll
      for (int kc = 0; kc < 4; kc++)
        a2[s][kc] = *(const bf16x8*)(p2 + (size_t)((s * 4 + kc) * 64) * 8);

    __syncthreads();

    // ---- Phase C: conv2 rows r0..r0+3 from the 6 ring slots ----
    int rowoff[6];
    {
      int s0 = (r0) % 6;
#pragma unroll
      for (int yr = 0; yr < 6; yr++) {
        int s = s0 + yr;
        if (s >= 6) s -= 6;
        rowoff[yr] = s * Y1ROW;
      }
    }
    __builtin_amdgcn_s_setprio(1);
#pragma unroll
    for (int h = 0; h < 2; h++) {
      const int xg = h * 16 + ln;
      const unsigned short* rp[6];
#pragma unroll
      for (int yr = 0; yr < 6; yr++) rp[yr] = &y1[0][0][0] + rowoff[yr] + q * 8;
      int pco[3];
#pragma unroll
      for (int dx = 0; dx < 3; dx++) {
        int pc = xg + dx;            // phys col; 33 wraps to shared zero col 0
        if (pc == 33) pc = 0;
        pco[dx] = pc * 136;
      }
      f32x4 A0 = cb2r, A1 = cb2r, A2 = cb2r, A3 = cb2r;
#pragma unroll
      for (int yr = 0; yr < 6; yr++)
#pragma unroll
        for (int kc = 0; kc < 4; kc++)
#pragma unroll
          for (int dx = 0; dx < 3; dx++) {
            bf16x8 fr = *(const bf16x8*)(rp[yr] + pco[dx] + kc * 32);
#pragma unroll
            for (int dy = 0; dy < 3; dy++) {
              const int rr = yr - dy;
              if (rr < 0 || rr > 3) continue;
              f32x4& ac = (rr == 0) ? A0 : ((rr == 1) ? A1 : ((rr == 2) ? A2 : A3));
              ac = MFMA(a2[dy * 3 + dx][kc], fr, ac, 0, 0, 0);
            }
          }
#pragma unroll
      for (int rr = 0; rr < 4; rr++) {
        const int grow = r0 + rr;
        const float rm0 = (grow <= 10) ? 1.f : 0.f;
        const float rm1 = (grow >= 10 && grow <= 21) ? 1.f : 0.f;
        const float rm2 = (grow >= 21) ? 1.f : 0.f;
        f32x4 v = (rr == 0) ? A0 : ((rr == 1) ? A1 : ((rr == 2) ? A2 : A3));
        v[0] = fmaxf(v[0], 0.f);
        v[1] = fmaxf(v[1], 0.f);
        v[2] = fmaxf(v[2], 0.f);
        v[3] = fmaxf(v[3], 0.f);
        if (h == 0) {
          PL0 += v * rm0; PL1 += v * rm1; PL2 += v * rm2;
        } else {
          PH0 += v * rm0; PH1 += v * rm1; PH2 += v * rm2;
        }
      }
    }
    __builtin_amdgcn_s_setprio(0);
    __syncthreads();
  }

  // ---- final pool: col masks + one 16-lane butterfly + direct stores ----
  const float mA0 = (ln <= 10) ? 1.f : 0.f;
  const float mA1 = (ln >= 10) ? 1.f : 0.f;
  const float mB1 = (ln <= 5) ? 1.f : 0.f;
  const float mB2 = (ln >= 5) ? 1.f : 0.f;
  f32x4 t00 = PL0 * mA0, t01 = PL0 * mA1 + PH0 * mB1, t02 = PH0 * mB2;
  f32x4 t10 = PL1 * mA0, t11 = PL1 * mA1 + PH1 * mB1, t12 = PH1 * mB2;
  f32x4 t20 = PL2 * mA0, t21 = PL2 * mA1 + PH2 * mB1, t22 = PH2 * mB2;

  {
    f32x4* tv[9] = {&t00, &t01, &t02, &t10, &t11, &t12, &t20, &t21, &t22};
#pragma unroll
    for (int i = 0; i < 9; i++) {
      f32x4& v = *tv[i];
#pragma unroll
      for (int c = 0; c < 4; c++) {
        float s = v[c];
        s += __shfl_xor(s, 1, 64);
        s += __shfl_xor(s, 2, 64);
        s += __shfl_xor(s, 4, 64);
        s += __shfl_xor(s, 8, 64);
        v[c] = s;
      }
    }
  }

  float* yp = ypool + (size_t)b * 576 + (w * 16 + q * 4) * 9;
#define PWRITE(tv, ph, pw)                                                      \
  if (ln == (ph * 3 + pw)) {                                                    \
    const float dv = 1.f / (float)(((ph == 1) ? 12 : 11) * ((pw == 1) ? 12 : 11)); \
    yp[0 * 9 + ph * 3 + pw] = tv[0] * dv;                                       \
    yp[1 * 9 + ph * 3 + pw] = tv[1] * dv;                                       \
    yp[2 * 9 + ph * 3 + pw] = tv[2] * dv;                                       \
    yp[3 * 9 + ph * 3 + pw] = tv[3] * dv;                                       \
  }
  PWRITE(t00, 0, 0) PWRITE(t01, 0, 1) PWRITE(t02, 0, 2)
  PWRITE(t10, 1, 0) PWRITE(t11, 1, 1) PWRITE(t12, 1, 2)
  PWRITE(t20, 2, 0) PWRITE(t21, 2, 1) PWRITE(t22, 2, 2)
#undef PWRITE
}

// ---------------------------------------------------------------------------
// K4: out = ypool @ wo + bo.  j-split x2: 1024 blocks (4 blocks/CU), each
// block computes 288 of 576 output cols for 4 rows (keeps 8-acc ILP while
// doubling occupancy; per-block weight footprint halves to 663 KB, L2-hit).
// ---------------------------------------------------------------------------
__global__ __launch_bounds__(256) void k_out(
    const float* __restrict__ ypool, const float* __restrict__ wo,
    const float* __restrict__ bo, float* __restrict__ out) {
  __shared__ float ys[4][576];
  const int t = threadIdx.x;
  const int b0 = (blockIdx.x >> 1) * 4;
  const int j0 = (blockIdx.x & 1) * 288;
  for (int e = t; e < 4 * 576; e += 256) {
    int r = e / 576, i = e % 576;
    ys[r][i] = ypool[(size_t)(b0 + r) * 576 + i];
  }
  __syncthreads();
  float a0[4], aT[4];
  {
    float bb0 = bo[j0 + t];
    float bbT = (t < 32) ? bo[j0 + 256 + t] : 0.f;
#pragma unroll
    for (int r = 0; r < 4; r++) { a0[r] = bb0; aT[r] = bbT; }
  }
#pragma unroll 2
  for (int i = 0; i < 576; i++) {
    const float* wr = wo + (size_t)i * 576;
    float w0 = wr[j0 + t];
    float g[4];
#pragma unroll
    for (int r = 0; r < 4; r++) g[r] = ys[r][i];
#pragma unroll
    for (int r = 0; r < 4; r++) a0[r] = fmaf(g[r], w0, a0[r]);
    if (t < 32) {  // sub-wave tail: uniform branch within half-wave
      float wT = wr[j0 + 256 + t];
#pragma unroll
      for (int r = 0; r < 4; r++) aT[r] = fmaf(g[r], wT, aT[r]);
    }
  }
#pragma unroll
  for (int r = 0; r < 4; r++) {
    float* orow = out + (size_t)(b0 + r) * 576;
    orow[j0 + t] = a0[r];
    if (t < 32) orow[j0 + 256 + t] = aT[r];
  }
}

extern "C" void kernel_launch(void* const* d_in, const int* in_sizes, int n_in,
                              void* d_out, int out_size, void* d_ws, size_t ws_size,
                              hipStream_t stream) {
  (void)in_sizes; (void)n_in; (void)out_size;
  const float* feat = (const float*)d_in[0];
  const float* cell = (const float*)d_in[1];
  const float* gaze = (const float*)d_in[2];
  const float* w1   = (const float*)d_in[3];
  const float* b1   = (const float*)d_in[4];
  const float* w2   = (const float*)d_in[5];
  const float* b2   = (const float*)d_in[6];
  const float* wv   = (const float*)d_in[7];
  const float* bv   = (const float*)d_in[8];
  const float* ws1  = (const float*)d_in[9];
  const float* bs1  = (const float*)d_in[10];
  const float* ws2  = (const float*)d_in[11];
  const float* bs2  = (const float*)d_in[12];
  const float* ck1  = (const float*)d_in[13];
  const float* cb1  = (const float*)d_in[14];
  const float* ck2  = (const float*)d_in[15];
  const float* cb2  = (const float*)d_in[16];
  const float* wo   = (const float*)d_in[17];
  const float* bo   = (const float*)d_in[18];

  float* out0    = (float*)d_out;                    // (B,576)
  float* updated = out0 + (size_t)NB * 576;          // (B,16,32,32)
  float* wvout   = (float*)d_ws;                     // B*1936 f32
  float* ypool   = wvout + (size_t)NB * NMK;         // B*576 f32
  unsigned short* ap1 = (unsigned short*)(ypool + (size_t)NB * 576);  // 20480 bf16
  unsigned short* ap2 = ap1 + 20480;                                  // 73728 bf16
  unsigned short* ubf = ap2 + 73728;  // CHUNK*34*34*16 bf16 (halo NHWC, reused)

  // Peak-workspace control: ubf is reused across batch chunks (stream order
  // serializes producer k_update / consumer k_conv3). Prefer full batch;
  // shrink if workspace is tight. (96.6 MB peak, proven rounds 6-8.)
  const size_t fixed_bytes = ((size_t)NB * (NMK + 576)) * 4 + (size_t)94208 * 2;
  const size_t wsz = ws_size ? ws_size : ((size_t)1 << 30);
  int chunk = 2048;
  while (chunk > 128 && fixed_bytes + (size_t)chunk * 36992 > wsz) chunk >>= 1;

  k_pack<<<dim3(368), dim3(256), 0, stream>>>(ck1, ck2, ap1, ap2);
  k_mlp<<<dim3(NB / 2), dim3(256), 0, stream>>>(feat, gaze, w1, b1, w2, b2, wv, bv, wvout);
  for (int b0 = 0; b0 < NB; b0 += chunk) {
    const int n = (NB - b0 < chunk) ? (NB - b0) : chunk;
    k_update<<<dim3(n), dim3(256), 0, stream>>>(
        cell + (size_t)b0 * 16384, gaze + (size_t)b0 * 2,
        wvout + (size_t)b0 * NMK, ws1, bs1, ws2, bs2,
        updated + (size_t)b0 * 16384, ubf);
    k_conv3<<<dim3(n), dim3(256), 0, stream>>>(
        ubf, ap1, cb1, ap2, cb2, ypool + (size_t)b0 * 576);
  }
  k_out<<<dim3(NB / 4 * 2), dim3(256), 0, stream>>>(ypool, wo, bo, out0);
}